// Round 14
// baseline (448.285 us; speedup 1.0000x reference)
//
#include <hip/hip_runtime.h>
#include <math.h>

#define RAWF 92
#define CF 64
#define NBRF 41
#define MN 24
#define HD 128

typedef short short8 __attribute__((ext_vector_type(8)));
typedef float f32x4 __attribute__((ext_vector_type(4)));
#define MFMA_BF16 __builtin_amdgcn_mfma_f32_16x16x32_bf16

__device__ __forceinline__ void lds_fence() {
  asm volatile("s_waitcnt lgkmcnt(0)" ::: "memory");
  __builtin_amdgcn_wave_barrier();
}

__device__ __forceinline__ float wsum64(float v) {
#pragma unroll
  for (int m = 32; m >= 1; m >>= 1) v += __shfl_xor(v, m, 64);
  return v;
}

// raw v_rcp_f32 (~1ulp) -- avoids IEEE div expansion
__device__ __forceinline__ float sigm(float x) {
  return __builtin_amdgcn_rcpf(1.f + __expf(-x));
}
// guard-free softplus: max(x,0)+log(1+exp(-|x|)) -- no overflow, no select
__device__ __forceinline__ float sftp(float x) {
  return fmaxf(x, 0.f) + __logf(1.f + __expf(-fabsf(x)));
}

__device__ __forceinline__ ushort f2b(float f) {  // RNE float->bf16
  unsigned u = __float_as_uint(f);
  return (ushort)((u + 0x7FFFu + ((u >> 16) & 1u)) >> 16);
}

__device__ __forceinline__ unsigned cvtpk(float lo, float hi) {
  unsigned u;
  asm("v_cvt_pk_bf16_f32 %0, %1, %2" : "=v"(u) : "v"(lo), "v"(hi));
  return u;
}

// ------------------------------------------------ weight transpose+cast (once)
// foldBe: write be into We's k==41 row (paired with nbf col41 = 1.0)
__global__ __launch_bounds__(256) void k_prep(
    const float* __restrict__ Wn, const float* __restrict__ We,
    const float* __restrict__ Wg, const float* __restrict__ Wm,
    const float* __restrict__ be, ushort* __restrict__ Wt, int foldBe) {
  int bid = blockIdx.x, layer = bid >> 2, mat = bid & 3;
  const float* src;
  int Krows = 64;
  if (mat == 0) src = Wn + layer * 4096;
  else if (mat == 1) { src = We + layer * NBRF * 64; Krows = NBRF; }
  else if (mat == 2) src = Wg + layer * 4096;
  else src = Wm + layer * 4096;
  ushort* dst = Wt + bid * 4096;
  for (int i = threadIdx.x; i < 4096; i += 256) {
    int n = i >> 6, k = i & 63;
    float v;
    if (mat == 1 && foldBe && k == NBRF) v = be[layer * 64 + n];
    else v = (k < Krows) ? src[k * 64 + n] : 0.f;
    dst[n * 64 + k] = f2b(v);
  }
}

__global__ __launch_bounds__(256) void k_prep_c(
    const float* __restrict__ Wc, ushort* __restrict__ Wtc) {
  int layer = blockIdx.x;
  const float* src = Wc + layer * 4096;
  ushort* dst = Wtc + layer * 4096;
  for (int i = threadIdx.x; i < 4096; i += 256) {
    int n = i >> 6, k = i & 63;
    dst[n * 64 + k] = f2b(src[k * 64 + n]);
  }
}

__global__ __launch_bounds__(256) void k_prep_emb(
    const float* __restrict__ Wemb, ushort* __restrict__ Wet) {
  for (int i = threadIdx.x; i < 64 * 96; i += 256) {
    int n = i / 96, k = i - n * 96;
    Wet[n * 96 + k] = (k < RAWF) ? f2b(Wemb[k * 64 + n]) : (ushort)0;
  }
}

// readout weights: W1t [n=128][k=64], W2t [n=64][k=128] bf16 transposed
__global__ __launch_bounds__(256) void k_prep_ro(
    const float* __restrict__ Wr1, const float* __restrict__ Wr2,
    ushort* __restrict__ W1t, ushort* __restrict__ W2t) {
  for (int i = blockIdx.x * 256 + threadIdx.x; i < 8192; i += gridDim.x * 256) {
    int n = i >> 6, k = i & 63;
    W1t[i] = f2b(Wr1[k * 128 + n]);
    int n2 = i >> 7, k2 = i & 127;
    W2t[n2 * 128 + k2] = f2b(Wr2[k2 * 64 + n2]);
  }
}

// atom_fea f32 [N][92] -> bf16 [N][96] (zero-pad)
__global__ __launch_bounds__(256) void k_prep_af(
    const float* __restrict__ af, ushort* __restrict__ afb, int nAtoms) {
  int a = blockIdx.x * 8 + (threadIdx.x >> 5);
  int cp = threadIdx.x & 31;
  if (a >= nAtoms) return;
#pragma unroll
  for (int j = 0; j < 3; ++j) {
    int c = 3 * cp + j;
    float v = (c < RAWF) ? af[(size_t)a * RAWF + c] : 0.f;
    afb[(size_t)a * 96 + c] = f2b(v);
  }
}

// ------------------------------------------------ nbr_fea f32 -> bf16 [rows][48]
__global__ __launch_bounds__(256) void k_prep_nbrf2(
    const float* __restrict__ nbrf, ushort* __restrict__ nbf, unsigned nrows,
    int fold) {
  unsigned nblk = nrows * 6;
  unsigned stride = gridDim.x * 256;
  unsigned one = fold ? 0x3F80u : 0u;
  for (unsigned o = blockIdx.x * 256 + threadIdx.x; o < nblk; o += stride) {
    unsigned row = (unsigned)(((unsigned long long)o * 2863311531ull) >> 34);
    unsigned c = o - row * 6u;
    const float* src = nbrf + (size_t)row * NBRF + c * 8;
    union { unsigned u[4]; short8 s8; } pk;
    if (c < 5) {
      float v0 = src[0], v1 = src[1], v2 = src[2], v3 = src[3];
      float v4 = src[4], v5 = src[5], v6 = src[6], v7 = src[7];
      pk.u[0] = cvtpk(v0, v1); pk.u[1] = cvtpk(v2, v3);
      pk.u[2] = cvtpk(v4, v5); pk.u[3] = cvtpk(v6, v7);
    } else {
      pk.u[0] = (unsigned)f2b(src[0]) | (one << 16);
      pk.u[1] = 0; pk.u[2] = 0; pk.u[3] = 0;
    }
    *reinterpret_cast<short8*>(nbf + (size_t)o * 8) = pk.s8;
  }
}

// ------------------------------------------------ embed via MFMA (16 atoms/wave)
__global__ __launch_bounds__(256) void k_embed2(
    const ushort* __restrict__ afb, const ushort* __restrict__ Wet,
    const float* __restrict__ bemb, float* __restrict__ h, int nAtoms) {
  int tid = threadIdx.x, w = tid >> 6, l = tid & 63, g = l >> 4, c15 = l & 15;
  int abase = (blockIdx.x * 4 + w) * 16;
  if (abase >= nAtoms) return;
  int atom = abase + c15;
  int ar = (atom < nAtoms) ? atom : (nAtoms - 1);
  short8 a[3];
#pragma unroll
  for (int ks = 0; ks < 3; ++ks)
    a[ks] = *reinterpret_cast<const short8*>(afb + (size_t)ar * 96 + ks * 32 + g * 8);
  short8 W[3][4];
#pragma unroll
  for (int ks = 0; ks < 3; ++ks)
#pragma unroll
    for (int nt = 0; nt < 4; ++nt)
      W[ks][nt] = *reinterpret_cast<const short8*>(Wet + (nt * 16 + c15) * 96 + ks * 32 + g * 8);
#pragma unroll
  for (int nt = 0; nt < 4; ++nt) {
    float b = bemb[nt * 16 + c15];
    f32x4 acc = {b, b, b, b};
    acc = MFMA_BF16(a[0], W[0][nt], acc, 0, 0, 0);
    acc = MFMA_BF16(a[1], W[1][nt], acc, 0, 0, 0);
    acc = MFMA_BF16(a[2], W[2][nt], acc, 0, 0, 0);
#pragma unroll
    for (int r = 0; r < 4; ++r) {
      int ao = abase + 4 * g + r;
      if (ao < nAtoms) h[(size_t)ao * 64 + nt * 16 + c15] = acc[r];
    }
  }
}

// ------------------------------------------------ LN + phi_c via MFMA (LDS-free)
__global__ __launch_bounds__(256) void k_lnphic2(
    const float* __restrict__ h, const float* __restrict__ lns,
    const float* __restrict__ lnb, const ushort* __restrict__ Wtc,
    const float* __restrict__ bc, ushort* __restrict__ xbf,
    float* __restrict__ pc, int nAtoms) {
  int tid = threadIdx.x, w = tid >> 6, l = tid & 63, g = l >> 4, c15 = l & 15;
  int abase = (blockIdx.x * 4 + w) * 16;
  if (abase >= nAtoms) return;
  int atom = abase + c15;
  int ar = (atom < nAtoms) ? atom : (nAtoms - 1);
  const float* hr = h + (size_t)ar * 64;
  float4 hA0 = *(const float4*)(hr + 8 * g);
  float4 hA1 = *(const float4*)(hr + 8 * g + 4);
  float4 hB0 = *(const float4*)(hr + 32 + 8 * g);
  float4 hB1 = *(const float4*)(hr + 32 + 8 * g + 4);
  float s = hA0.x + hA0.y + hA0.z + hA0.w + hA1.x + hA1.y + hA1.z + hA1.w +
            hB0.x + hB0.y + hB0.z + hB0.w + hB1.x + hB1.y + hB1.z + hB1.w;
  float sq = hA0.x * hA0.x + hA0.y * hA0.y + hA0.z * hA0.z + hA0.w * hA0.w +
             hA1.x * hA1.x + hA1.y * hA1.y + hA1.z * hA1.z + hA1.w * hA1.w +
             hB0.x * hB0.x + hB0.y * hB0.y + hB0.z * hB0.z + hB0.w * hB0.w +
             hB1.x * hB1.x + hB1.y * hB1.y + hB1.z * hB1.z + hB1.w * hB1.w;
  s += __shfl_xor(s, 16, 64); s += __shfl_xor(s, 32, 64);
  sq += __shfl_xor(sq, 16, 64); sq += __shfl_xor(sq, 32, 64);
  float mu = s * (1.f / 64.f);
  float var = sq * (1.f / 64.f) - mu * mu;
  float rs = rsqrtf(var + 1e-6f);
  float4 sA0 = *(const float4*)(lns + 8 * g), sA1 = *(const float4*)(lns + 8 * g + 4);
  float4 sB0 = *(const float4*)(lns + 32 + 8 * g), sB1 = *(const float4*)(lns + 32 + 8 * g + 4);
  float4 bA0 = *(const float4*)(lnb + 8 * g), bA1 = *(const float4*)(lnb + 8 * g + 4);
  float4 bB0 = *(const float4*)(lnb + 32 + 8 * g), bB1 = *(const float4*)(lnb + 32 + 8 * g + 4);
  float xA[8], xB[8];
  xA[0] = (hA0.x - mu) * rs * sA0.x + bA0.x; xA[1] = (hA0.y - mu) * rs * sA0.y + bA0.y;
  xA[2] = (hA0.z - mu) * rs * sA0.z + bA0.z; xA[3] = (hA0.w - mu) * rs * sA0.w + bA0.w;
  xA[4] = (hA1.x - mu) * rs * sA1.x + bA1.x; xA[5] = (hA1.y - mu) * rs * sA1.y + bA1.y;
  xA[6] = (hA1.z - mu) * rs * sA1.z + bA1.z; xA[7] = (hA1.w - mu) * rs * sA1.w + bA1.w;
  xB[0] = (hB0.x - mu) * rs * sB0.x + bB0.x; xB[1] = (hB0.y - mu) * rs * sB0.y + bB0.y;
  xB[2] = (hB0.z - mu) * rs * sB0.z + bB0.z; xB[3] = (hB0.w - mu) * rs * sB0.w + bB0.w;
  xB[4] = (hB1.x - mu) * rs * sB1.x + bB1.x; xB[5] = (hB1.y - mu) * rs * sB1.y + bB1.y;
  xB[6] = (hB1.z - mu) * rs * sB1.z + bB1.z; xB[7] = (hB1.w - mu) * rs * sB1.w + bB1.w;
  union { unsigned u[4]; short8 s8; } pa, pb;
#pragma unroll
  for (int i = 0; i < 4; ++i) {
    pa.u[i] = cvtpk(xA[2 * i], xA[2 * i + 1]);
    pb.u[i] = cvtpk(xB[2 * i], xB[2 * i + 1]);
  }
  if (atom < nAtoms) {
    *reinterpret_cast<short8*>(xbf + (size_t)atom * 64 + 8 * g) = pa.s8;
    *reinterpret_cast<short8*>(xbf + (size_t)atom * 64 + 32 + 8 * g) = pb.s8;
  }
  short8 W[2][4];
#pragma unroll
  for (int ks = 0; ks < 2; ++ks)
#pragma unroll
    for (int nt = 0; nt < 4; ++nt)
      W[ks][nt] = *reinterpret_cast<const short8*>(Wtc + (nt * 16 + c15) * 64 + ks * 32 + g * 8);
#pragma unroll
  for (int nt = 0; nt < 4; ++nt) {
    float b = bc[nt * 16 + c15];
    f32x4 acc = {b, b, b, b};
    acc = MFMA_BF16(pa.s8, W[0][nt], acc, 0, 0, 0);
    acc = MFMA_BF16(pb.s8, W[1][nt], acc, 0, 0, 0);
#pragma unroll
    for (int r = 0; r < 4; ++r) {
      int ao = abase + 4 * g + r;
      if (ao < nAtoms) pc[(size_t)ao * 64 + nt * 16 + c15] = acc[r];
    }
  }
}

// ------------------------------------------------ conv v13: v12 + phase-B
// weight frags hoisted to regs (48->16 LDS reads) + guard-free sftp.
__global__ __launch_bounds__(256, 3) void k_conv_mfma13(
    const ushort* __restrict__ xbf, const float* __restrict__ pcg,
    const ushort* __restrict__ nbf, const int* __restrict__ idx,
    const ushort* __restrict__ Wt, const float* __restrict__ bn,
    const float* __restrict__ bg, const float* __restrict__ bm,
    float* __restrict__ h) {
  __shared__ ushort Wl[4 * 4096];  // [mat][n][k ^ ((n&7)<<3)]
  __shared__ float pcs[8 * 64];    // this block's phi_c rows
  __shared__ float bns[64];        // bn broadcast
  int tid = threadIdx.x;
  for (int u = tid; u < 2048; u += 256) {
    int mat = u >> 9, n = (u >> 3) & 63, k8 = u & 7;
    short8 v = *reinterpret_cast<const short8*>(Wt + (size_t)u * 8);
    *reinterpret_cast<short8*>(&Wl[mat * 4096 + n * 64 + ((k8 * 8) ^ ((n & 7) << 3))]) = v;
  }
  int atom0 = blockIdx.x * 8;
  for (int u = tid; u < 512; u += 256)
    pcs[u] = pcg[(size_t)atom0 * 64 + u];
  if (tid < 64) bns[tid] = bn[tid];
  __syncthreads();

  int w = tid >> 6, l = tid & 63, g = l >> 4, c15 = l & 15;
  int swzW = (c15 & 7) << 3;
  int s0 = ((l & 16) << 1) + c15, s1 = s0 + 16;
  bool hi = (l >= 32);
  size_t rowg0 = (size_t)atom0 * MN + 48 * w;
  int nb0 = idx[rowg0 + c15];
  int nb1 = idx[rowg0 + 16 + c15];
  int nb2 = idx[rowg0 + 32 + c15];

  short8 aI0[3], aI1[3];
  // ---- phase A: swapped MFMA (LDS weights, be-folded E) + lane exchange ----
  {
    short8 z8 = {0, 0, 0, 0, 0, 0, 0, 0};
#pragma unroll
    for (int t = 0; t < 3; ++t) {
      int nbt = (t == 0) ? nb0 : ((t == 1) ? nb1 : nb2);
      const ushort* xr = xbf + (size_t)nbt * 64;
      short8 xf0 = *reinterpret_cast<const short8*>(xr + g * 8);
      short8 xf1 = *reinterpret_cast<const short8*>(xr + 32 + g * 8);
      const ushort* er = nbf + (rowg0 + 16 * t + c15) * 48;
      short8 ef0 = *reinterpret_cast<const short8*>(er + g * 8);
      short8 ef1 = (g < 2) ? *reinterpret_cast<const short8*>(er + 32 + g * 8) : z8;
      int la = (t == 0) ? 2 * w : (t == 2) ? (2 * w + 1)
               : ((c15 < 8) ? 2 * w : 2 * w + 1);
      unsigned u01[4], u23[4];
#pragma unroll
      for (int nt = 0; nt < 4; ++nt) {
        int n64 = (nt * 16 + c15) * 64;
        short8 Wn0 = *reinterpret_cast<const short8*>(&Wl[0 * 4096 + n64 + ((g * 8) ^ swzW)]);
        short8 Wn1 = *reinterpret_cast<const short8*>(&Wl[0 * 4096 + n64 + ((32 + g * 8) ^ swzW)]);
        f32x4 P = *reinterpret_cast<const f32x4*>(&bns[nt * 16 + 4 * g]);
        P = MFMA_BF16(Wn0, xf0, P, 0, 0, 0);
        P = MFMA_BF16(Wn1, xf1, P, 0, 0, 0);
        short8 We0 = *reinterpret_cast<const short8*>(&Wl[1 * 4096 + n64 + ((g * 8) ^ swzW)]);
        short8 We1 = *reinterpret_cast<const short8*>(&Wl[1 * 4096 + n64 + ((32 + g * 8) ^ swzW)]);
        f32x4 E = {0.f, 0.f, 0.f, 0.f};  // be arrives via nbf col41 * We row41
        E = MFMA_BF16(We0, ef0, E, 0, 0, 0);
        E = MFMA_BF16(We1, ef1, E, 0, 0, 0);
        f32x4 pv = *reinterpret_cast<const f32x4*>(&pcs[la * 64 + nt * 16 + 4 * g]);
        u01[nt] = cvtpk(pv[0] * (P[0] * E[0]), pv[1] * (P[1] * E[1]));
        u23[nt] = cvtpk(pv[2] * (P[2] * E[2]), pv[3] * (P[3] * E[3]));
      }
      union { unsigned u[4]; short8 s8; } A0, A1;
      {
        unsigned a0 = __shfl(u01[0], s0), b0 = __shfl(u01[1], s0);
        unsigned a1 = __shfl(u23[0], s0), b1 = __shfl(u23[1], s0);
        unsigned a2 = __shfl(u01[0], s1), b2 = __shfl(u01[1], s1);
        unsigned a3 = __shfl(u23[0], s1), b3 = __shfl(u23[1], s1);
        A0.u[0] = hi ? b0 : a0; A0.u[1] = hi ? b1 : a1;
        A0.u[2] = hi ? b2 : a2; A0.u[3] = hi ? b3 : a3;
      }
      {
        unsigned a0 = __shfl(u01[2], s0), b0 = __shfl(u01[3], s0);
        unsigned a1 = __shfl(u23[2], s0), b1 = __shfl(u23[3], s0);
        unsigned a2 = __shfl(u01[2], s1), b2 = __shfl(u01[3], s1);
        unsigned a3 = __shfl(u23[2], s1), b3 = __shfl(u23[3], s1);
        A1.u[0] = hi ? b0 : a0; A1.u[1] = hi ? b1 : a1;
        A1.u[2] = hi ? b2 : a2; A1.u[3] = hi ? b3 : a3;
      }
      aI0[t] = A0.s8;
      aI1[t] = A1.s8;
    }
  }

  // ---- phase B: gate/mag, weights hoisted to regs (read once, use 3x) ----
  float asT0[4] = {0.f, 0.f, 0.f, 0.f};
  float asT1[4] = {0.f, 0.f, 0.f, 0.f};
  float asT2[4] = {0.f, 0.f, 0.f, 0.f};
  {
    float bgv[4], bmv[4];
    short8 WgF[2][4], WmF[2][4];
#pragma unroll
    for (int nt = 0; nt < 4; ++nt) {
      bgv[nt] = bg[nt * 16 + c15];
      bmv[nt] = bm[nt * 16 + c15];
      int n64 = (nt * 16 + c15) * 64;
      WgF[0][nt] = *reinterpret_cast<const short8*>(&Wl[2 * 4096 + n64 + ((g * 8) ^ swzW)]);
      WgF[1][nt] = *reinterpret_cast<const short8*>(&Wl[2 * 4096 + n64 + ((32 + g * 8) ^ swzW)]);
      WmF[0][nt] = *reinterpret_cast<const short8*>(&Wl[3 * 4096 + n64 + ((g * 8) ^ swzW)]);
      WmF[1][nt] = *reinterpret_cast<const short8*>(&Wl[3 * 4096 + n64 + ((32 + g * 8) ^ swzW)]);
    }
#pragma unroll
    for (int t = 0; t < 3; ++t) {
#pragma unroll
      for (int nt = 0; nt < 4; ++nt) {
        f32x4 G = {bgv[nt], bgv[nt], bgv[nt], bgv[nt]};
        G = MFMA_BF16(aI0[t], WgF[0][nt], G, 0, 0, 0);
        G = MFMA_BF16(aI1[t], WgF[1][nt], G, 0, 0, 0);
        f32x4 S = {bmv[nt], bmv[nt], bmv[nt], bmv[nt]};
        S = MFMA_BF16(aI0[t], WmF[0][nt], S, 0, 0, 0);
        S = MFMA_BF16(aI1[t], WmF[1][nt], S, 0, 0, 0);
#pragma unroll
        for (int r = 0; r < 4; ++r) {
          float o = sigm(G[r]) * sftp(S[r]);
          if (t == 0) asT0[nt] += o;
          else if (t == 1) asT1[nt] += o;
          else asT2[nt] += o;
        }
      }
    }
  }
#pragma unroll
  for (int nt = 0; nt < 4; ++nt) {
    float v0 = asT0[nt] + ((g < 2) ? asT1[nt] : 0.f);
    float v1 = asT2[nt] + ((g < 2) ? 0.f : asT1[nt]);
    v0 += __shfl_xor(v0, 16, 64); v0 += __shfl_xor(v0, 32, 64);
    v1 += __shfl_xor(v1, 16, 64); v1 += __shfl_xor(v1, 32, 64);
    if (l < 16) {
      size_t o0 = (size_t)(atom0 + 2 * w) * 64 + nt * 16 + l;
      h[o0] += v0;
      h[o0 + 64] += v1;
    }
  }
}

// ------------------------------------------------ conv v2 (fallback, proven;
// expects fold=0 prep: be added explicitly here)
__global__ __launch_bounds__(256) void k_conv_mfma2(
    const ushort* __restrict__ xbf, const float* __restrict__ pcg,
    const ushort* __restrict__ nbf, const int* __restrict__ idx,
    const ushort* __restrict__ Wt, const float* __restrict__ bn,
    const float* __restrict__ be, const float* __restrict__ bg,
    const float* __restrict__ bm, float* __restrict__ h) {
  __shared__ ushort Inter[192 * 64];
  int tid = threadIdx.x;
  int w = tid >> 6, l = tid & 63, g = l >> 4, c15 = l & 15;
  int atom0 = blockIdx.x * 8;
  size_t rowg0 = (size_t)atom0 * MN + 48 * w;
  int myidx = (l < 48) ? idx[rowg0 + l] : 0;
  float bnv[4], bev[4], bgv[4], bmv[4], pca0[4], pca1[4];
#pragma unroll
  for (int nt = 0; nt < 4; ++nt) {
    int col = nt * 16 + c15;
    bnv[nt] = bn[col]; bev[nt] = be[col]; bgv[nt] = bg[col]; bmv[nt] = bm[col];
    pca0[nt] = pcg[(size_t)(atom0 + 2 * w) * 64 + col];
    pca1[nt] = pcg[(size_t)(atom0 + 2 * w + 1) * 64 + col];
  }
  ushort* InterW = Inter + 48 * 64 * w;
  int swzr = (c15 & 7) << 3;
  {
    short8 WnF[2][4], WeF[2][4];
#pragma unroll
    for (int ks = 0; ks < 2; ++ks)
#pragma unroll
      for (int nt = 0; nt < 4; ++nt) {
        int n = nt * 16 + c15, k0 = ks * 32 + g * 8;
        WnF[ks][nt] = *reinterpret_cast<const short8*>(Wt + 0 * 4096 + n * 64 + k0);
        WeF[ks][nt] = *reinterpret_cast<const short8*>(Wt + 1 * 4096 + n * 64 + k0);
      }
    short8 z8 = {0, 0, 0, 0, 0, 0, 0, 0};
#pragma unroll
    for (int t = 0; t < 3; ++t) {
      int rl = 16 * t + c15;
      int nbv = __shfl(myidx, rl, 64);
      const ushort* xr = xbf + (size_t)nbv * 64;
      short8 aN0 = *reinterpret_cast<const short8*>(xr + g * 8);
      short8 aN1 = *reinterpret_cast<const short8*>(xr + 32 + g * 8);
      const ushort* er = nbf + (rowg0 + rl) * 48;
      short8 aE0 = *reinterpret_cast<const short8*>(er + g * 8);
      short8 aE1 = (g < 2) ? *reinterpret_cast<const short8*>(er + 32 + g * 8) : z8;
      f32x4 P[4], E[4];
#pragma unroll
      for (int nt = 0; nt < 4; ++nt) {
        f32x4 z = {0.f, 0.f, 0.f, 0.f};
        P[nt] = MFMA_BF16(aN0, WnF[0][nt], z, 0, 0, 0);
        P[nt] = MFMA_BF16(aN1, WnF[1][nt], P[nt], 0, 0, 0);
        E[nt] = MFMA_BF16(aE0, WeF[0][nt], z, 0, 0, 0);
        E[nt] = MFMA_BF16(aE1, WeF[1][nt], E[nt], 0, 0, 0);
      }
#pragma unroll
      for (int nt = 0; nt < 4; ++nt)
#pragma unroll
        for (int r = 0; r < 4; ++r) {
          int grow = 16 * t + 4 * g + r;
          float pn = P[nt][r] + bnv[nt];
          float pe = E[nt][r] + bev[nt];
          float pcv = (grow < 24) ? pca0[nt] : pca1[nt];
          int col = nt * 16 + c15;
          InterW[grow * 64 + (col ^ (((4 * g + r) & 7) << 3))] = f2b(pcv * pn * pe);
        }
    }
  }
  lds_fence();
  float as0[4] = {0.f, 0.f, 0.f, 0.f}, as1[4] = {0.f, 0.f, 0.f, 0.f};
  {
    short8 WgF[2][4], WmF[2][4];
#pragma unroll
    for (int ks = 0; ks < 2; ++ks)
#pragma unroll
      for (int nt = 0; nt < 4; ++nt) {
        int n = nt * 16 + c15, k0 = ks * 32 + g * 8;
        WgF[ks][nt] = *reinterpret_cast<const short8*>(Wt + 2 * 4096 + n * 64 + k0);
        WmF[ks][nt] = *reinterpret_cast<const short8*>(Wt + 3 * 4096 + n * 64 + k0);
      }
#pragma unroll
    for (int t = 0; t < 3; ++t) {
      const ushort* rowp = InterW + (16 * t + c15) * 64;
      short8 aI0 = *reinterpret_cast<const short8*>(rowp + ((g * 8) ^ swzr));
      short8 aI1 = *reinterpret_cast<const short8*>(rowp + ((32 + g * 8) ^ swzr));
      f32x4 G[4], S[4];
#pragma unroll
      for (int nt = 0; nt < 4; ++nt) {
        f32x4 z = {0.f, 0.f, 0.f, 0.f};
        G[nt] = MFMA_BF16(aI0, WgF[0][nt], z, 0, 0, 0);
        G[nt] = MFMA_BF16(aI1, WgF[1][nt], G[nt], 0, 0, 0);
        S[nt] = MFMA_BF16(aI0, WmF[0][nt], z, 0, 0, 0);
        S[nt] = MFMA_BF16(aI1, WmF[1][nt], S[nt], 0, 0, 0);
      }
#pragma unroll
      for (int nt = 0; nt < 4; ++nt)
#pragma unroll
        for (int r = 0; r < 4; ++r) {
          int grow = 16 * t + 4 * g + r;
          float gate = sigm(G[nt][r] + bgv[nt]);
          float mag = sftp(S[nt][r] + bmv[nt]);
          float o = gate * mag;
          as0[nt] += (grow < 24) ? o : 0.f;
          as1[nt] += (grow < 24) ? 0.f : o;
        }
    }
  }
#pragma unroll
  for (int nt = 0; nt < 4; ++nt) {
    float v0 = as0[nt];
    v0 += __shfl_xor(v0, 16, 64); v0 += __shfl_xor(v0, 32, 64);
    float v1 = as1[nt];
    v1 += __shfl_xor(v1, 16, 64); v1 += __shfl_xor(v1, 32, 64);
    if (l < 16) {
      size_t o0 = (size_t)(atom0 + 2 * w) * 64 + nt * 16 + l;
      h[o0] += v0;
      h[o0 + 64] += v1;
    }
  }
}

// ---------------------------------------------------------------- embed (fp32 fallback)
__global__ __launch_bounds__(256) void k_embed(
    const float* __restrict__ af, const float* __restrict__ Wemb,
    const float* __restrict__ bemb, float* __restrict__ h, int nAtoms) {
  __shared__ float Ws[96 * 64];
  __shared__ float rows[4][96];
  int tid = threadIdx.x;
  for (int t = tid; t < 96 * 64; t += 256) {
    int r = t >> 6;
    Ws[t] = (r < RAWF) ? Wemb[t] : 0.f;
  }
  __syncthreads();
  int w = tid >> 6, j = tid & 63;
  float bj = bemb[j];
  int wg = (blockIdx.x << 2) + w, nw = gridDim.x << 2;
  for (int n = wg; n < nAtoms; n += nw) {
    const float* ar = af + (size_t)n * RAWF;
    rows[w][j] = ar[j];
    if (j < 32) rows[w][64 + j] = (64 + j < RAWF) ? ar[64 + j] : 0.f;
    lds_fence();
    float acc = bj;
#pragma unroll
    for (int kk = 0; kk < 24; ++kk) {
      float4 q = *reinterpret_cast<const float4*>(&rows[w][kk * 4]);
      const float* base = &Ws[(kk * 4) * 64 + j];
      acc += q.x * base[0] + q.y * base[64] + q.z * base[128] + q.w * base[192];
    }
    h[(size_t)n * 64 + j] = acc;
    lds_fence();
  }
}

// ---------------------------------------------------------------- LN + phi_c (fp32 fallback)
__global__ __launch_bounds__(256) void k_ln_phic(
    const float* __restrict__ h, const float* __restrict__ lns,
    const float* __restrict__ lnb, const float* __restrict__ Wc,
    const float* __restrict__ bc, ushort* __restrict__ xbf,
    float* __restrict__ pc, int nAtoms) {
  __shared__ float Ws[64 * 64];
  __shared__ float rows[4][64];
  int tid = threadIdx.x;
  for (int t = tid; t < 1024; t += 256)
    reinterpret_cast<float4*>(Ws)[t] = reinterpret_cast<const float4*>(Wc)[t];
  __syncthreads();
  int w = tid >> 6, j = tid & 63;
  float sj = lns[j], bj = lnb[j], bcj = bc[j];
  int wg = (blockIdx.x << 2) + w, nw = gridDim.x << 2;
  for (int n = wg; n < nAtoms; n += nw) {
    float hv = h[(size_t)n * 64 + j];
    float mu = wsum64(hv) * (1.f / 64.f);
    float d = hv - mu;
    float var = wsum64(d * d) * (1.f / 64.f);
    float xv = d * rsqrtf(var + 1e-6f) * sj + bj;
    xbf[(size_t)n * 64 + j] = f2b(xv);
    rows[w][j] = xv;
    lds_fence();
    float acc = bcj;
#pragma unroll
    for (int kk = 0; kk < 16; ++kk) {
      float4 q = *reinterpret_cast<const float4*>(&rows[w][kk * 4]);
      const float* base = &Ws[(kk * 4) * 64 + j];
      acc += q.x * base[0] + q.y * base[64] + q.z * base[128] + q.w * base[192];
    }
    pc[(size_t)n * 64 + j] = acc;
    lds_fence();
  }
}

// ---------------------------------------------------------------- readout v2 (MFMA)
__global__ __launch_bounds__(256) void k_readout2(
    const float* __restrict__ h, const ushort* __restrict__ W1t,
    const ushort* __restrict__ W2t, const float* __restrict__ br1,
    const float* __restrict__ br2, const float* __restrict__ Wr3,
    float* __restrict__ partials, int nAtoms) {
  __shared__ ushort Wl1[128 * 64];
  __shared__ ushort Wl2[64 * 128];
  __shared__ ushort R1[4][16 * 136];
  __shared__ float wsum[4];
  int tid = threadIdx.x;
  for (int u = tid; u < 1024; u += 256) {
    int n = u >> 3, k8 = u & 7;
    short8 v = *reinterpret_cast<const short8*>(W1t + u * 8);
    *reinterpret_cast<short8*>(&Wl1[n * 64 + ((k8 * 8) ^ ((n & 7) << 3))]) = v;
  }
  for (int u = tid; u < 1024; u += 256) {
    int n = u >> 4, k8 = u & 15;
    short8 v = *reinterpret_cast<const short8*>(W2t + u * 8);
    *reinterpret_cast<short8*>(&Wl2[n * 128 + ((k8 * 8) ^ ((n & 7) << 3))]) = v;
  }
  __syncthreads();
  int w = tid >> 6, l = tid & 63, g = l >> 4, c15 = l & 15;
  int swz = (c15 & 7) << 3;
  int abase = blockIdx.x * 64 + w * 16;
  bool active = abase < nAtoms;
  int ab = active ? abase : 0;
  int atom = ab + c15;
  int ar = (atom < nAtoms) ? atom : (nAtoms - 1);
  const float* hr = h + (size_t)ar * 64;
  short8 a[2];
#pragma unroll
  for (int ks = 0; ks < 2; ++ks) {
    float4 p0 = *(const float4*)(hr + ks * 32 + g * 8);
    float4 p1 = *(const float4*)(hr + ks * 32 + g * 8 + 4);
    union { unsigned u[4]; short8 s8; } pk;
    pk.u[0] = cvtpk(p0.x, p0.y); pk.u[1] = cvtpk(p0.z, p0.w);
    pk.u[2] = cvtpk(p1.x, p1.y); pk.u[3] = cvtpk(p1.z, p1.w);
    a[ks] = pk.s8;
  }
  ushort* R1w = R1[w];
#pragma unroll
  for (int nt = 0; nt < 8; ++nt) {
    float b = br1[nt * 16 + c15];
    f32x4 acc = {b, b, b, b};
    short8 B0 = *reinterpret_cast<const short8*>(&Wl1[(nt * 16 + c15) * 64 + ((g * 8) ^ swz)]);
    short8 B1 = *reinterpret_cast<const short8*>(&Wl1[(nt * 16 + c15) * 64 + ((32 + g * 8) ^ swz)]);
    acc = MFMA_BF16(a[0], B0, acc, 0, 0, 0);
    acc = MFMA_BF16(a[1], B1, acc, 0, 0, 0);
#pragma unroll
    for (int r = 0; r < 4; ++r) {
      int row = 4 * g + r;
      R1w[row * 136 + ((nt * 16 + c15) ^ ((row & 7) << 3))] = f2b(sftp(acc[r]));
    }
  }
  lds_fence();
  short8 a2[4];
#pragma unroll
  for (int ks = 0; ks < 4; ++ks)
    a2[ks] = *reinterpret_cast<const short8*>(&R1w[c15 * 136 + ((ks * 32 + g * 8) ^ swz)]);
  float lsum = 0.f;
#pragma unroll
  for (int nt = 0; nt < 4; ++nt) {
    float w3v = Wr3[nt * 16 + c15];
    float b = br2[nt * 16 + c15];
    f32x4 acc = {b, b, b, b};
#pragma unroll
    for (int ks = 0; ks < 4; ++ks) {
      short8 B = *reinterpret_cast<const short8*>(&Wl2[(nt * 16 + c15) * 128 + ((ks * 32 + g * 8) ^ swz)]);
      acc = MFMA_BF16(a2[ks], B, acc, 0, 0, 0);
    }
#pragma unroll
    for (int r = 0; r < 4; ++r) {
      int ao = ab + 4 * g + r;
      if (active && ao < nAtoms) lsum += sftp(acc[r]) * w3v;
    }
  }
  float tot = wsum64(lsum);
  if (l == 0) wsum[w] = tot;
  __syncthreads();
  if (tid == 0)
    partials[blockIdx.x] = wsum[0] + wsum[1] + wsum[2] + wsum[3];
}

// ---------------------------------------------------------------- readout (fp32 fallback)
__global__ __launch_bounds__(256) void k_readout(
    const float* __restrict__ h, const float* __restrict__ Wr1,
    const float* __restrict__ br1, const float* __restrict__ Wr2,
    const float* __restrict__ br2, const float* __restrict__ Wr3,
    float* __restrict__ partials, int nAtoms) {
  __shared__ float W1[64 * 128];
  __shared__ float W2[128 * 64];
  __shared__ float w3s[64];
  __shared__ float rowbuf[4][128];
  __shared__ float wsum[4];
  int tid = threadIdx.x;
  for (int t = tid; t < 2048; t += 256) {
    reinterpret_cast<float4*>(W1)[t] = reinterpret_cast<const float4*>(Wr1)[t];
    reinterpret_cast<float4*>(W2)[t] = reinterpret_cast<const float4*>(Wr2)[t];
  }
  if (tid < 64) w3s[tid] = Wr3[tid];
  __syncthreads();
  int w = tid >> 6, j = tid & 63;
  float b1a = br1[j], b1b = br1[64 + j], b2 = br2[j];
  float w3 = w3s[j];
  float lsum = 0.f;
  int wg = (blockIdx.x << 2) + w, nw = gridDim.x << 2;
  for (int n = wg; n < nAtoms; n += nw) {
    lds_fence();
    rowbuf[w][j] = h[(size_t)n * 64 + j];
    lds_fence();
    float a0 = b1a, a1 = b1b;
#pragma unroll
    for (int kk = 0; kk < 16; ++kk) {
      float4 q = *reinterpret_cast<const float4*>(&rowbuf[w][kk * 4]);
      const float* base = &W1[(kk * 4) * 128 + j];
      a0 += q.x * base[0] + q.y * base[128] + q.z * base[256] + q.w * base[384];
      a1 += q.x * base[64] + q.y * base[192] + q.z * base[320] + q.w * base[448];
    }
    a0 = sftp(a0);
    a1 = sftp(a1);
    lds_fence();
    rowbuf[w][j] = a0;
    rowbuf[w][64 + j] = a1;
    lds_fence();
    float a2 = b2;
#pragma unroll
    for (int kk = 0; kk < 32; ++kk) {
      float4 q = *reinterpret_cast<const float4*>(&rowbuf[w][kk * 4]);
      const float* base = &W2[(kk * 4) * 64 + j];
      a2 += q.x * base[0] + q.y * base[64] + q.z * base[128] + q.w * base[192];
    }
    lsum += sftp(a2) * w3;
  }
  float tot = wsum64(lsum);
  if (j == 0) wsum[w] = tot;
  __syncthreads();
  if (tid == 0)
    partials[blockIdx.x] = wsum[0] + wsum[1] + wsum[2] + wsum[3];
}

__global__ __launch_bounds__(256) void k_final(const float* __restrict__ partials,
                                               int nparts, float* __restrict__ out,
                                               const float* __restrict__ br3,
                                               float invN) {
  __shared__ float s[256];
  float v = 0.f;
  for (int t = threadIdx.x; t < nparts; t += 256) v += partials[t];
  s[threadIdx.x] = v;
  __syncthreads();
  for (int off = 128; off > 0; off >>= 1) {
    if (threadIdx.x < off) s[threadIdx.x] += s[threadIdx.x + off];
    __syncthreads();
  }
  if (threadIdx.x == 0) out[0] = s[0] * invN + br3[0];
}

// ---------------------------------------------------------------- launch
extern "C" void kernel_launch(void* const* d_in, const int* in_sizes, int n_in,
                              void* d_out, int out_size, void* d_ws, size_t ws_size,
                              hipStream_t stream) {
  const float* af   = (const float*)d_in[0];
  const float* nbrf = (const float*)d_in[1];
  const int*   idx  = (const int*)d_in[2];
  const float* Wemb = (const float*)d_in[3];
  const float* bemb = (const float*)d_in[4];
  const float* ln_s = (const float*)d_in[5];
  const float* ln_b = (const float*)d_in[6];
  const float* Wc   = (const float*)d_in[7];
  const float* bc   = (const float*)d_in[8];
  const float* Wn   = (const float*)d_in[9];
  const float* bn   = (const float*)d_in[10];
  const float* We   = (const float*)d_in[11];
  const float* be   = (const float*)d_in[12];
  const float* Wg   = (const float*)d_in[13];
  const float* bg   = (const float*)d_in[14];
  const float* Wm   = (const float*)d_in[15];
  const float* bm   = (const float*)d_in[16];
  const float* Wr1  = (const float*)d_in[17];
  const float* br1  = (const float*)d_in[18];
  const float* Wr2  = (const float*)d_in[19];
  const float* br2  = (const float*)d_in[20];
  const float* Wr3  = (const float*)d_in[21];
  const float* br3  = (const float*)d_in[22];

  int N = in_sizes[0] / RAWF;  // 50000
  size_t rows = (size_t)N * MN;
  float* ws = (float*)d_ws;
  size_t nc = (size_t)N * CF;
  float* h   = ws;
  float* pcb = ws + nc;
  float* partials = ws + 2 * nc;                 // 1024 floats
  ushort* Wt   = (ushort*)(partials + 1024);     // 12*4096 bf16
  ushort* Wtc  = Wt + 12 * 4096;                 // 3*4096
  ushort* Wet  = Wtc + 3 * 4096;                 // 64*96
  ushort* xbf  = Wet + 64 * 96;                  // nc
  ushort* afb  = xbf + nc;                       // N*96
  ushort* nbf  = afb + (size_t)N * 96;           // rows*48
  ushort* W1t  = nbf + rows * 48;                // 8192
  ushort* W2t  = W1t + 8192;                     // 8192
  size_t need = (size_t)((char*)(W2t + 8192) - (char*)d_ws);
  bool full = ws_size >= need;
  const int RO_GRID = 512;
  int gw = (N + 63) / 64;

  k_prep<<<12, 256, 0, stream>>>(Wn, We, Wg, Wm, be, Wt, full ? 1 : 0);
  if (full) {
    k_prep_c<<<3, 256, 0, stream>>>(Wc, Wtc);
    k_prep_emb<<<1, 256, 0, stream>>>(Wemb, Wet);
    k_prep_ro<<<32, 256, 0, stream>>>(Wr1, Wr2, W1t, W2t);
    k_prep_af<<<(N + 7) / 8, 256, 0, stream>>>(af, afb, N);
    k_prep_nbrf2<<<2048, 256, 0, stream>>>(nbrf, nbf, (unsigned)rows, 1);
    k_embed2<<<gw, 256, 0, stream>>>(afb, Wet, bemb, h, N);
    for (int i = 0; i < 3; ++i) {
      k_lnphic2<<<gw, 256, 0, stream>>>(h, ln_s + i * 64, ln_b + i * 64,
                                        Wtc + (size_t)i * 4096, bc + i * 64,
                                        xbf, pcb, N);
      k_conv_mfma13<<<N / 8, 256, 0, stream>>>(xbf, pcb, nbf, idx,
                                               Wt + (size_t)i * 4 * 4096,
                                               bn + i * 64,
                                               bg + i * 64, bm + i * 64, h);
    }
    k_readout2<<<gw, 256, 0, stream>>>(h, W1t, W2t, br1, br2, Wr3,
                                       partials, N);
    k_final<<<1, 256, 0, stream>>>(partials, gw, (float*)d_out, br3, 1.f / N);
  } else {
    k_prep_nbrf2<<<2048, 256, 0, stream>>>(nbrf, nbf, (unsigned)rows, 0);
    k_embed<<<1024, 256, 0, stream>>>(af, Wemb, bemb, h, N);
    for (int i = 0; i < 3; ++i) {
      k_ln_phic<<<1024, 256, 0, stream>>>(h, ln_s + i * 64, ln_b + i * 64,
                                          Wc + i * 4096, bc + i * 64,
                                          xbf, pcb, N);
      k_conv_mfma2<<<N / 8, 256, 0, stream>>>(xbf, pcb, nbf, idx,
                                              Wt + (size_t)i * 4 * 4096,
                                              bn + i * 64, be + i * 64,
                                              bg + i * 64, bm + i * 64, h);
    }
    k_readout<<<RO_GRID, 256, 0, stream>>>(h, Wr1, br1, Wr2, br2, Wr3,
                                           partials, N);
    k_final<<<1, 256, 0, stream>>>(partials, RO_GRID, (float*)d_out, br3, 1.f / N);
  }
}

// Round 15
// 437.145 us; speedup vs baseline: 1.0255x; 1.0255x over previous
//
#include <hip/hip_runtime.h>
#include <math.h>

#define RAWF 92
#define CF 64
#define NBRF 41
#define MN 24
#define HD 128

typedef short short8 __attribute__((ext_vector_type(8)));
typedef float f32x4 __attribute__((ext_vector_type(4)));
#define MFMA_BF16 __builtin_amdgcn_mfma_f32_16x16x32_bf16

__device__ __forceinline__ void lds_fence() {
  asm volatile("s_waitcnt lgkmcnt(0)" ::: "memory");
  __builtin_amdgcn_wave_barrier();
}

__device__ __forceinline__ float wsum64(float v) {
#pragma unroll
  for (int m = 32; m >= 1; m >>= 1) v += __shfl_xor(v, m, 64);
  return v;
}

// raw v_rcp_f32 (~1ulp) -- avoids IEEE div expansion (v_div_scale/fmas/fixup)
__device__ __forceinline__ float sigm(float x) {
  return __builtin_amdgcn_rcpf(1.f + __expf(-x));
}
__device__ __forceinline__ float sftp(float x) { return x > 20.f ? x : __logf(1.f + __expf(x)); }

__device__ __forceinline__ ushort f2b(float f) {  // RNE float->bf16
  unsigned u = __float_as_uint(f);
  return (ushort)((u + 0x7FFFu + ((u >> 16) & 1u)) >> 16);
}

__device__ __forceinline__ unsigned cvtpk(float lo, float hi) {
  unsigned u;
  asm("v_cvt_pk_bf16_f32 %0, %1, %2" : "=v"(u) : "v"(lo), "v"(hi));
  return u;
}

// ------------------------------------------------ weight transpose+cast (once)
// foldBe: write be into We's k==41 row (paired with nbf col41 = 1.0)
__global__ __launch_bounds__(256) void k_prep(
    const float* __restrict__ Wn, const float* __restrict__ We,
    const float* __restrict__ Wg, const float* __restrict__ Wm,
    const float* __restrict__ be, ushort* __restrict__ Wt, int foldBe) {
  int bid = blockIdx.x, layer = bid >> 2, mat = bid & 3;
  const float* src;
  int Krows = 64;
  if (mat == 0) src = Wn + layer * 4096;
  else if (mat == 1) { src = We + layer * NBRF * 64; Krows = NBRF; }
  else if (mat == 2) src = Wg + layer * 4096;
  else src = Wm + layer * 4096;
  ushort* dst = Wt + bid * 4096;
  for (int i = threadIdx.x; i < 4096; i += 256) {
    int n = i >> 6, k = i & 63;
    float v;
    if (mat == 1 && foldBe && k == NBRF) v = be[layer * 64 + n];
    else v = (k < Krows) ? src[k * 64 + n] : 0.f;
    dst[n * 64 + k] = f2b(v);
  }
}

__global__ __launch_bounds__(256) void k_prep_c(
    const float* __restrict__ Wc, ushort* __restrict__ Wtc) {
  int layer = blockIdx.x;
  const float* src = Wc + layer * 4096;
  ushort* dst = Wtc + layer * 4096;
  for (int i = threadIdx.x; i < 4096; i += 256) {
    int n = i >> 6, k = i & 63;
    dst[n * 64 + k] = f2b(src[k * 64 + n]);
  }
}

__global__ __launch_bounds__(256) void k_prep_emb(
    const float* __restrict__ Wemb, ushort* __restrict__ Wet) {
  for (int i = threadIdx.x; i < 64 * 96; i += 256) {
    int n = i / 96, k = i - n * 96;
    Wet[n * 96 + k] = (k < RAWF) ? f2b(Wemb[k * 64 + n]) : (ushort)0;
  }
}

// readout weights: W1t [n=128][k=64], W2t [n=64][k=128] bf16 transposed
__global__ __launch_bounds__(256) void k_prep_ro(
    const float* __restrict__ Wr1, const float* __restrict__ Wr2,
    ushort* __restrict__ W1t, ushort* __restrict__ W2t) {
  for (int i = blockIdx.x * 256 + threadIdx.x; i < 8192; i += gridDim.x * 256) {
    int n = i >> 6, k = i & 63;
    W1t[i] = f2b(Wr1[k * 128 + n]);
    int n2 = i >> 7, k2 = i & 127;
    W2t[n2 * 128 + k2] = f2b(Wr2[k2 * 64 + n2]);
  }
}

// atom_fea f32 [N][92] -> bf16 [N][96] (zero-pad)
__global__ __launch_bounds__(256) void k_prep_af(
    const float* __restrict__ af, ushort* __restrict__ afb, int nAtoms) {
  int a = blockIdx.x * 8 + (threadIdx.x >> 5);
  int cp = threadIdx.x & 31;
  if (a >= nAtoms) return;
#pragma unroll
  for (int j = 0; j < 3; ++j) {
    int c = 3 * cp + j;
    float v = (c < RAWF) ? af[(size_t)a * RAWF + c] : 0.f;
    afb[(size_t)a * 96 + c] = f2b(v);
  }
}

// ------------------------------------------------ nbr_fea f32 -> bf16 [rows][48]
__global__ __launch_bounds__(256) void k_prep_nbrf2(
    const float* __restrict__ nbrf, ushort* __restrict__ nbf, unsigned nrows,
    int fold) {
  unsigned nblk = nrows * 6;
  unsigned stride = gridDim.x * 256;
  unsigned one = fold ? 0x3F80u : 0u;
  for (unsigned o = blockIdx.x * 256 + threadIdx.x; o < nblk; o += stride) {
    unsigned row = (unsigned)(((unsigned long long)o * 2863311531ull) >> 34);
    unsigned c = o - row * 6u;
    const float* src = nbrf + (size_t)row * NBRF + c * 8;
    union { unsigned u[4]; short8 s8; } pk;
    if (c < 5) {
      float v0 = src[0], v1 = src[1], v2 = src[2], v3 = src[3];
      float v4 = src[4], v5 = src[5], v6 = src[6], v7 = src[7];
      pk.u[0] = cvtpk(v0, v1); pk.u[1] = cvtpk(v2, v3);
      pk.u[2] = cvtpk(v4, v5); pk.u[3] = cvtpk(v6, v7);
    } else {
      pk.u[0] = (unsigned)f2b(src[0]) | (one << 16);
      pk.u[1] = 0; pk.u[2] = 0; pk.u[3] = 0;
    }
    *reinterpret_cast<short8*>(nbf + (size_t)o * 8) = pk.s8;
  }
}

// ------------------------------------------------ embed via MFMA (16 atoms/wave)
__global__ __launch_bounds__(256) void k_embed2(
    const ushort* __restrict__ afb, const ushort* __restrict__ Wet,
    const float* __restrict__ bemb, float* __restrict__ h, int nAtoms) {
  int tid = threadIdx.x, w = tid >> 6, l = tid & 63, g = l >> 4, c15 = l & 15;
  int abase = (blockIdx.x * 4 + w) * 16;
  if (abase >= nAtoms) return;
  int atom = abase + c15;
  int ar = (atom < nAtoms) ? atom : (nAtoms - 1);
  short8 a[3];
#pragma unroll
  for (int ks = 0; ks < 3; ++ks)
    a[ks] = *reinterpret_cast<const short8*>(afb + (size_t)ar * 96 + ks * 32 + g * 8);
  short8 W[3][4];
#pragma unroll
  for (int ks = 0; ks < 3; ++ks)
#pragma unroll
    for (int nt = 0; nt < 4; ++nt)
      W[ks][nt] = *reinterpret_cast<const short8*>(Wet + (nt * 16 + c15) * 96 + ks * 32 + g * 8);
#pragma unroll
  for (int nt = 0; nt < 4; ++nt) {
    float b = bemb[nt * 16 + c15];
    f32x4 acc = {b, b, b, b};
    acc = MFMA_BF16(a[0], W[0][nt], acc, 0, 0, 0);
    acc = MFMA_BF16(a[1], W[1][nt], acc, 0, 0, 0);
    acc = MFMA_BF16(a[2], W[2][nt], acc, 0, 0, 0);
#pragma unroll
    for (int r = 0; r < 4; ++r) {
      int ao = abase + 4 * g + r;
      if (ao < nAtoms) h[(size_t)ao * 64 + nt * 16 + c15] = acc[r];
    }
  }
}

// ------------------------------------------------ LN + phi_c via MFMA (LDS-free)
__global__ __launch_bounds__(256) void k_lnphic2(
    const float* __restrict__ h, const float* __restrict__ lns,
    const float* __restrict__ lnb, const ushort* __restrict__ Wtc,
    const float* __restrict__ bc, ushort* __restrict__ xbf,
    float* __restrict__ pc, int nAtoms) {
  int tid = threadIdx.x, w = tid >> 6, l = tid & 63, g = l >> 4, c15 = l & 15;
  int abase = (blockIdx.x * 4 + w) * 16;
  if (abase >= nAtoms) return;
  int atom = abase + c15;
  int ar = (atom < nAtoms) ? atom : (nAtoms - 1);
  const float* hr = h + (size_t)ar * 64;
  float4 hA0 = *(const float4*)(hr + 8 * g);
  float4 hA1 = *(const float4*)(hr + 8 * g + 4);
  float4 hB0 = *(const float4*)(hr + 32 + 8 * g);
  float4 hB1 = *(const float4*)(hr + 32 + 8 * g + 4);
  float s = hA0.x + hA0.y + hA0.z + hA0.w + hA1.x + hA1.y + hA1.z + hA1.w +
            hB0.x + hB0.y + hB0.z + hB0.w + hB1.x + hB1.y + hB1.z + hB1.w;
  float sq = hA0.x * hA0.x + hA0.y * hA0.y + hA0.z * hA0.z + hA0.w * hA0.w +
             hA1.x * hA1.x + hA1.y * hA1.y + hA1.z * hA1.z + hA1.w * hA1.w +
             hB0.x * hB0.x + hB0.y * hB0.y + hB0.z * hB0.z + hB0.w * hB0.w +
             hB1.x * hB1.x + hB1.y * hB1.y + hB1.z * hB1.z + hB1.w * hB1.w;
  s += __shfl_xor(s, 16, 64); s += __shfl_xor(s, 32, 64);
  sq += __shfl_xor(sq, 16, 64); sq += __shfl_xor(sq, 32, 64);
  float mu = s * (1.f / 64.f);
  float var = sq * (1.f / 64.f) - mu * mu;
  float rs = rsqrtf(var + 1e-6f);
  float4 sA0 = *(const float4*)(lns + 8 * g), sA1 = *(const float4*)(lns + 8 * g + 4);
  float4 sB0 = *(const float4*)(lns + 32 + 8 * g), sB1 = *(const float4*)(lns + 32 + 8 * g + 4);
  float4 bA0 = *(const float4*)(lnb + 8 * g), bA1 = *(const float4*)(lnb + 8 * g + 4);
  float4 bB0 = *(const float4*)(lnb + 32 + 8 * g), bB1 = *(const float4*)(lnb + 32 + 8 * g + 4);
  float xA[8], xB[8];
  xA[0] = (hA0.x - mu) * rs * sA0.x + bA0.x; xA[1] = (hA0.y - mu) * rs * sA0.y + bA0.y;
  xA[2] = (hA0.z - mu) * rs * sA0.z + bA0.z; xA[3] = (hA0.w - mu) * rs * sA0.w + bA0.w;
  xA[4] = (hA1.x - mu) * rs * sA1.x + bA1.x; xA[5] = (hA1.y - mu) * rs * sA1.y + bA1.y;
  xA[6] = (hA1.z - mu) * rs * sA1.z + bA1.z; xA[7] = (hA1.w - mu) * rs * sA1.w + bA1.w;
  xB[0] = (hB0.x - mu) * rs * sB0.x + bB0.x; xB[1] = (hB0.y - mu) * rs * sB0.y + bB0.y;
  xB[2] = (hB0.z - mu) * rs * sB0.z + bB0.z; xB[3] = (hB0.w - mu) * rs * sB0.w + bB0.w;
  xB[4] = (hB1.x - mu) * rs * sB1.x + bB1.x; xB[5] = (hB1.y - mu) * rs * sB1.y + bB1.y;
  xB[6] = (hB1.z - mu) * rs * sB1.z + bB1.z; xB[7] = (hB1.w - mu) * rs * sB1.w + bB1.w;
  union { unsigned u[4]; short8 s8; } pa, pb;
#pragma unroll
  for (int i = 0; i < 4; ++i) {
    pa.u[i] = cvtpk(xA[2 * i], xA[2 * i + 1]);
    pb.u[i] = cvtpk(xB[2 * i], xB[2 * i + 1]);
  }
  if (atom < nAtoms) {
    *reinterpret_cast<short8*>(xbf + (size_t)atom * 64 + 8 * g) = pa.s8;
    *reinterpret_cast<short8*>(xbf + (size_t)atom * 64 + 32 + 8 * g) = pb.s8;
  }
  short8 W[2][4];
#pragma unroll
  for (int ks = 0; ks < 2; ++ks)
#pragma unroll
    for (int nt = 0; nt < 4; ++nt)
      W[ks][nt] = *reinterpret_cast<const short8*>(Wtc + (nt * 16 + c15) * 64 + ks * 32 + g * 8);
#pragma unroll
  for (int nt = 0; nt < 4; ++nt) {
    float b = bc[nt * 16 + c15];
    f32x4 acc = {b, b, b, b};
    acc = MFMA_BF16(pa.s8, W[0][nt], acc, 0, 0, 0);
    acc = MFMA_BF16(pb.s8, W[1][nt], acc, 0, 0, 0);
#pragma unroll
    for (int r = 0; r < 4; ++r) {
      int ao = abase + 4 * g + r;
      if (ao < nAtoms) pc[(size_t)ao * 64 + nt * 16 + c15] = acc[r];
    }
  }
}

// ------------------------------------------------ conv v12 (proven best, R13):
// LDS weights + reg-exchange transpose + fast sigm, launch_bounds(256,3).
__global__ __launch_bounds__(256, 3) void k_conv_mfma12(
    const ushort* __restrict__ xbf, const float* __restrict__ pcg,
    const ushort* __restrict__ nbf, const int* __restrict__ idx,
    const ushort* __restrict__ Wt, const float* __restrict__ bn,
    const float* __restrict__ bg, const float* __restrict__ bm,
    float* __restrict__ h) {
  __shared__ ushort Wl[4 * 4096];  // [mat][n][k ^ ((n&7)<<3)]
  __shared__ float pcs[8 * 64];    // this block's phi_c rows
  __shared__ float bns[64];        // bn broadcast
  int tid = threadIdx.x;
  for (int u = tid; u < 2048; u += 256) {
    int mat = u >> 9, n = (u >> 3) & 63, k8 = u & 7;
    short8 v = *reinterpret_cast<const short8*>(Wt + (size_t)u * 8);
    *reinterpret_cast<short8*>(&Wl[mat * 4096 + n * 64 + ((k8 * 8) ^ ((n & 7) << 3))]) = v;
  }
  int atom0 = blockIdx.x * 8;
  for (int u = tid; u < 512; u += 256)
    pcs[u] = pcg[(size_t)atom0 * 64 + u];
  if (tid < 64) bns[tid] = bn[tid];
  __syncthreads();

  int w = tid >> 6, l = tid & 63, g = l >> 4, c15 = l & 15;
  int swzW = (c15 & 7) << 3;
  int s0 = ((l & 16) << 1) + c15, s1 = s0 + 16;
  bool hi = (l >= 32);
  size_t rowg0 = (size_t)atom0 * MN + 48 * w;
  int nb0 = idx[rowg0 + c15];
  int nb1 = idx[rowg0 + 16 + c15];
  int nb2 = idx[rowg0 + 32 + c15];

  short8 aI0[3], aI1[3];
  // ---- phase A: swapped MFMA (LDS weights, be-folded E) + lane exchange ----
  {
    short8 z8 = {0, 0, 0, 0, 0, 0, 0, 0};
#pragma unroll
    for (int t = 0; t < 3; ++t) {
      int nbt = (t == 0) ? nb0 : ((t == 1) ? nb1 : nb2);
      const ushort* xr = xbf + (size_t)nbt * 64;
      short8 xf0 = *reinterpret_cast<const short8*>(xr + g * 8);
      short8 xf1 = *reinterpret_cast<const short8*>(xr + 32 + g * 8);
      const ushort* er = nbf + (rowg0 + 16 * t + c15) * 48;
      short8 ef0 = *reinterpret_cast<const short8*>(er + g * 8);
      short8 ef1 = (g < 2) ? *reinterpret_cast<const short8*>(er + 32 + g * 8) : z8;
      int la = (t == 0) ? 2 * w : (t == 2) ? (2 * w + 1)
               : ((c15 < 8) ? 2 * w : 2 * w + 1);
      unsigned u01[4], u23[4];
#pragma unroll
      for (int nt = 0; nt < 4; ++nt) {
        int n64 = (nt * 16 + c15) * 64;
        short8 Wn0 = *reinterpret_cast<const short8*>(&Wl[0 * 4096 + n64 + ((g * 8) ^ swzW)]);
        short8 Wn1 = *reinterpret_cast<const short8*>(&Wl[0 * 4096 + n64 + ((32 + g * 8) ^ swzW)]);
        f32x4 P = *reinterpret_cast<const f32x4*>(&bns[nt * 16 + 4 * g]);
        P = MFMA_BF16(Wn0, xf0, P, 0, 0, 0);
        P = MFMA_BF16(Wn1, xf1, P, 0, 0, 0);
        short8 We0 = *reinterpret_cast<const short8*>(&Wl[1 * 4096 + n64 + ((g * 8) ^ swzW)]);
        short8 We1 = *reinterpret_cast<const short8*>(&Wl[1 * 4096 + n64 + ((32 + g * 8) ^ swzW)]);
        f32x4 E = {0.f, 0.f, 0.f, 0.f};  // be arrives via nbf col41 * We row41
        E = MFMA_BF16(We0, ef0, E, 0, 0, 0);
        E = MFMA_BF16(We1, ef1, E, 0, 0, 0);
        f32x4 pv = *reinterpret_cast<const f32x4*>(&pcs[la * 64 + nt * 16 + 4 * g]);
        u01[nt] = cvtpk(pv[0] * (P[0] * E[0]), pv[1] * (P[1] * E[1]));
        u23[nt] = cvtpk(pv[2] * (P[2] * E[2]), pv[3] * (P[3] * E[3]));
      }
      union { unsigned u[4]; short8 s8; } A0, A1;
      {
        unsigned a0 = __shfl(u01[0], s0), b0 = __shfl(u01[1], s0);
        unsigned a1 = __shfl(u23[0], s0), b1 = __shfl(u23[1], s0);
        unsigned a2 = __shfl(u01[0], s1), b2 = __shfl(u01[1], s1);
        unsigned a3 = __shfl(u23[0], s1), b3 = __shfl(u23[1], s1);
        A0.u[0] = hi ? b0 : a0; A0.u[1] = hi ? b1 : a1;
        A0.u[2] = hi ? b2 : a2; A0.u[3] = hi ? b3 : a3;
      }
      {
        unsigned a0 = __shfl(u01[2], s0), b0 = __shfl(u01[3], s0);
        unsigned a1 = __shfl(u23[2], s0), b1 = __shfl(u23[3], s0);
        unsigned a2 = __shfl(u01[2], s1), b2 = __shfl(u01[3], s1);
        unsigned a3 = __shfl(u23[2], s1), b3 = __shfl(u23[3], s1);
        A1.u[0] = hi ? b0 : a0; A1.u[1] = hi ? b1 : a1;
        A1.u[2] = hi ? b2 : a2; A1.u[3] = hi ? b3 : a3;
      }
      aI0[t] = A0.s8;
      aI1[t] = A1.s8;
    }
  }

  // ---- phase B: gate/mag (LDS weights) + per-t accumulators ----
  float asT0[4] = {0.f, 0.f, 0.f, 0.f};
  float asT1[4] = {0.f, 0.f, 0.f, 0.f};
  float asT2[4] = {0.f, 0.f, 0.f, 0.f};
  {
    float bgv[4], bmv[4];
#pragma unroll
    for (int nt = 0; nt < 4; ++nt) {
      bgv[nt] = bg[nt * 16 + c15];
      bmv[nt] = bm[nt * 16 + c15];
    }
#pragma unroll
    for (int t = 0; t < 3; ++t) {
#pragma unroll
      for (int nt = 0; nt < 4; ++nt) {
        int n64 = (nt * 16 + c15) * 64;
        short8 Wg0 = *reinterpret_cast<const short8*>(&Wl[2 * 4096 + n64 + ((g * 8) ^ swzW)]);
        short8 Wg1 = *reinterpret_cast<const short8*>(&Wl[2 * 4096 + n64 + ((32 + g * 8) ^ swzW)]);
        f32x4 G = {bgv[nt], bgv[nt], bgv[nt], bgv[nt]};
        G = MFMA_BF16(aI0[t], Wg0, G, 0, 0, 0);
        G = MFMA_BF16(aI1[t], Wg1, G, 0, 0, 0);
        short8 Wm0 = *reinterpret_cast<const short8*>(&Wl[3 * 4096 + n64 + ((g * 8) ^ swzW)]);
        short8 Wm1 = *reinterpret_cast<const short8*>(&Wl[3 * 4096 + n64 + ((32 + g * 8) ^ swzW)]);
        f32x4 S = {bmv[nt], bmv[nt], bmv[nt], bmv[nt]};
        S = MFMA_BF16(aI0[t], Wm0, S, 0, 0, 0);
        S = MFMA_BF16(aI1[t], Wm1, S, 0, 0, 0);
#pragma unroll
        for (int r = 0; r < 4; ++r) {
          float o = sigm(G[r]) * sftp(S[r]);
          if (t == 0) asT0[nt] += o;
          else if (t == 1) asT1[nt] += o;
          else asT2[nt] += o;
        }
      }
    }
  }
#pragma unroll
  for (int nt = 0; nt < 4; ++nt) {
    float v0 = asT0[nt] + ((g < 2) ? asT1[nt] : 0.f);
    float v1 = asT2[nt] + ((g < 2) ? 0.f : asT1[nt]);
    v0 += __shfl_xor(v0, 16, 64); v0 += __shfl_xor(v0, 32, 64);
    v1 += __shfl_xor(v1, 16, 64); v1 += __shfl_xor(v1, 32, 64);
    if (l < 16) {
      size_t o0 = (size_t)(atom0 + 2 * w) * 64 + nt * 16 + l;
      h[o0] += v0;
      h[o0 + 64] += v1;
    }
  }
}

// ------------------------------------------------ conv v2 (fallback, proven;
// expects fold=0 prep: be added explicitly here)
__global__ __launch_bounds__(256) void k_conv_mfma2(
    const ushort* __restrict__ xbf, const float* __restrict__ pcg,
    const ushort* __restrict__ nbf, const int* __restrict__ idx,
    const ushort* __restrict__ Wt, const float* __restrict__ bn,
    const float* __restrict__ be, const float* __restrict__ bg,
    const float* __restrict__ bm, float* __restrict__ h) {
  __shared__ ushort Inter[192 * 64];
  int tid = threadIdx.x;
  int w = tid >> 6, l = tid & 63, g = l >> 4, c15 = l & 15;
  int atom0 = blockIdx.x * 8;
  size_t rowg0 = (size_t)atom0 * MN + 48 * w;
  int myidx = (l < 48) ? idx[rowg0 + l] : 0;
  float bnv[4], bev[4], bgv[4], bmv[4], pca0[4], pca1[4];
#pragma unroll
  for (int nt = 0; nt < 4; ++nt) {
    int col = nt * 16 + c15;
    bnv[nt] = bn[col]; bev[nt] = be[col]; bgv[nt] = bg[col]; bmv[nt] = bm[col];
    pca0[nt] = pcg[(size_t)(atom0 + 2 * w) * 64 + col];
    pca1[nt] = pcg[(size_t)(atom0 + 2 * w + 1) * 64 + col];
  }
  ushort* InterW = Inter + 48 * 64 * w;
  int swzr = (c15 & 7) << 3;
  {
    short8 WnF[2][4], WeF[2][4];
#pragma unroll
    for (int ks = 0; ks < 2; ++ks)
#pragma unroll
      for (int nt = 0; nt < 4; ++nt) {
        int n = nt * 16 + c15, k0 = ks * 32 + g * 8;
        WnF[ks][nt] = *reinterpret_cast<const short8*>(Wt + 0 * 4096 + n * 64 + k0);
        WeF[ks][nt] = *reinterpret_cast<const short8*>(Wt + 1 * 4096 + n * 64 + k0);
      }
    short8 z8 = {0, 0, 0, 0, 0, 0, 0, 0};
#pragma unroll
    for (int t = 0; t < 3; ++t) {
      int rl = 16 * t + c15;
      int nbv = __shfl(myidx, rl, 64);
      const ushort* xr = xbf + (size_t)nbv * 64;
      short8 aN0 = *reinterpret_cast<const short8*>(xr + g * 8);
      short8 aN1 = *reinterpret_cast<const short8*>(xr + 32 + g * 8);
      const ushort* er = nbf + (rowg0 + rl) * 48;
      short8 aE0 = *reinterpret_cast<const short8*>(er + g * 8);
      short8 aE1 = (g < 2) ? *reinterpret_cast<const short8*>(er + 32 + g * 8) : z8;
      f32x4 P[4], E[4];
#pragma unroll
      for (int nt = 0; nt < 4; ++nt) {
        f32x4 z = {0.f, 0.f, 0.f, 0.f};
        P[nt] = MFMA_BF16(aN0, WnF[0][nt], z, 0, 0, 0);
        P[nt] = MFMA_BF16(aN1, WnF[1][nt], P[nt], 0, 0, 0);
        E[nt] = MFMA_BF16(aE0, WeF[0][nt], z, 0, 0, 0);
        E[nt] = MFMA_BF16(aE1, WeF[1][nt], E[nt], 0, 0, 0);
      }
#pragma unroll
      for (int nt = 0; nt < 4; ++nt)
#pragma unroll
        for (int r = 0; r < 4; ++r) {
          int grow = 16 * t + 4 * g + r;
          float pn = P[nt][r] + bnv[nt];
          float pe = E[nt][r] + bev[nt];
          float pcv = (grow < 24) ? pca0[nt] : pca1[nt];
          int col = nt * 16 + c15;
          InterW[grow * 64 + (col ^ (((4 * g + r) & 7) << 3))] = f2b(pcv * pn * pe);
        }
    }
  }
  lds_fence();
  float as0[4] = {0.f, 0.f, 0.f, 0.f}, as1[4] = {0.f, 0.f, 0.f, 0.f};
  {
    short8 WgF[2][4], WmF[2][4];
#pragma unroll
    for (int ks = 0; ks < 2; ++ks)
#pragma unroll
      for (int nt = 0; nt < 4; ++nt) {
        int n = nt * 16 + c15, k0 = ks * 32 + g * 8;
        WgF[ks][nt] = *reinterpret_cast<const short8*>(Wt + 2 * 4096 + n * 64 + k0);
        WmF[ks][nt] = *reinterpret_cast<const short8*>(Wt + 3 * 4096 + n * 64 + k0);
      }
#pragma unroll
    for (int t = 0; t < 3; ++t) {
      const ushort* rowp = InterW + (16 * t + c15) * 64;
      short8 aI0 = *reinterpret_cast<const short8*>(rowp + ((g * 8) ^ swzr));
      short8 aI1 = *reinterpret_cast<const short8*>(rowp + ((32 + g * 8) ^ swzr));
      f32x4 G[4], S[4];
#pragma unroll
      for (int nt = 0; nt < 4; ++nt) {
        f32x4 z = {0.f, 0.f, 0.f, 0.f};
        G[nt] = MFMA_BF16(aI0, WgF[0][nt], z, 0, 0, 0);
        G[nt] = MFMA_BF16(aI1, WgF[1][nt], G[nt], 0, 0, 0);
        S[nt] = MFMA_BF16(aI0, WmF[0][nt], z, 0, 0, 0);
        S[nt] = MFMA_BF16(aI1, WmF[1][nt], S[nt], 0, 0, 0);
      }
#pragma unroll
      for (int nt = 0; nt < 4; ++nt)
#pragma unroll
        for (int r = 0; r < 4; ++r) {
          int grow = 16 * t + 4 * g + r;
          float gate = sigm(G[nt][r] + bgv[nt]);
          float mag = sftp(S[nt][r] + bmv[nt]);
          float o = gate * mag;
          as0[nt] += (grow < 24) ? o : 0.f;
          as1[nt] += (grow < 24) ? 0.f : o;
        }
    }
  }
#pragma unroll
  for (int nt = 0; nt < 4; ++nt) {
    float v0 = as0[nt];
    v0 += __shfl_xor(v0, 16, 64); v0 += __shfl_xor(v0, 32, 64);
    float v1 = as1[nt];
    v1 += __shfl_xor(v1, 16, 64); v1 += __shfl_xor(v1, 32, 64);
    if (l < 16) {
      size_t o0 = (size_t)(atom0 + 2 * w) * 64 + nt * 16 + l;
      h[o0] += v0;
      h[o0 + 64] += v1;
    }
  }
}

// ---------------------------------------------------------------- embed (fp32 fallback)
__global__ __launch_bounds__(256) void k_embed(
    const float* __restrict__ af, const float* __restrict__ Wemb,
    const float* __restrict__ bemb, float* __restrict__ h, int nAtoms) {
  __shared__ float Ws[96 * 64];
  __shared__ float rows[4][96];
  int tid = threadIdx.x;
  for (int t = tid; t < 96 * 64; t += 256) {
    int r = t >> 6;
    Ws[t] = (r < RAWF) ? Wemb[t] : 0.f;
  }
  __syncthreads();
  int w = tid >> 6, j = tid & 63;
  float bj = bemb[j];
  int wg = (blockIdx.x << 2) + w, nw = gridDim.x << 2;
  for (int n = wg; n < nAtoms; n += nw) {
    const float* ar = af + (size_t)n * RAWF;
    rows[w][j] = ar[j];
    if (j < 32) rows[w][64 + j] = (64 + j < RAWF) ? ar[64 + j] : 0.f;
    lds_fence();
    float acc = bj;
#pragma unroll
    for (int kk = 0; kk < 24; ++kk) {
      float4 q = *reinterpret_cast<const float4*>(&rows[w][kk * 4]);
      const float* base = &Ws[(kk * 4) * 64 + j];
      acc += q.x * base[0] + q.y * base[64] + q.z * base[128] + q.w * base[192];
    }
    h[(size_t)n * 64 + j] = acc;
    lds_fence();
  }
}

// ---------------------------------------------------------------- LN + phi_c (fp32 fallback)
__global__ __launch_bounds__(256) void k_ln_phic(
    const float* __restrict__ h, const float* __restrict__ lns,
    const float* __restrict__ lnb, const float* __restrict__ Wc,
    const float* __restrict__ bc, ushort* __restrict__ xbf,
    float* __restrict__ pc, int nAtoms) {
  __shared__ float Ws[64 * 64];
  __shared__ float rows[4][64];
  int tid = threadIdx.x;
  for (int t = tid; t < 1024; t += 256)
    reinterpret_cast<float4*>(Ws)[t] = reinterpret_cast<const float4*>(Wc)[t];
  __syncthreads();
  int w = tid >> 6, j = tid & 63;
  float sj = lns[j], bj = lnb[j], bcj = bc[j];
  int wg = (blockIdx.x << 2) + w, nw = gridDim.x << 2;
  for (int n = wg; n < nAtoms; n += nw) {
    float hv = h[(size_t)n * 64 + j];
    float mu = wsum64(hv) * (1.f / 64.f);
    float d = hv - mu;
    float var = wsum64(d * d) * (1.f / 64.f);
    float xv = d * rsqrtf(var + 1e-6f) * sj + bj;
    xbf[(size_t)n * 64 + j] = f2b(xv);
    rows[w][j] = xv;
    lds_fence();
    float acc = bcj;
#pragma unroll
    for (int kk = 0; kk < 16; ++kk) {
      float4 q = *reinterpret_cast<const float4*>(&rows[w][kk * 4]);
      const float* base = &Ws[(kk * 4) * 64 + j];
      acc += q.x * base[0] + q.y * base[64] + q.z * base[128] + q.w * base[192];
    }
    pc[(size_t)n * 64 + j] = acc;
    lds_fence();
  }
}

// ---------------------------------------------------------------- readout v2 (MFMA)
__global__ __launch_bounds__(256) void k_readout2(
    const float* __restrict__ h, const ushort* __restrict__ W1t,
    const ushort* __restrict__ W2t, const float* __restrict__ br1,
    const float* __restrict__ br2, const float* __restrict__ Wr3,
    float* __restrict__ partials, int nAtoms) {
  __shared__ ushort Wl1[128 * 64];
  __shared__ ushort Wl2[64 * 128];
  __shared__ ushort R1[4][16 * 136];
  __shared__ float wsum[4];
  int tid = threadIdx.x;
  for (int u = tid; u < 1024; u += 256) {
    int n = u >> 3, k8 = u & 7;
    short8 v = *reinterpret_cast<const short8*>(W1t + u * 8);
    *reinterpret_cast<short8*>(&Wl1[n * 64 + ((k8 * 8) ^ ((n & 7) << 3))]) = v;
  }
  for (int u = tid; u < 1024; u += 256) {
    int n = u >> 4, k8 = u & 15;
    short8 v = *reinterpret_cast<const short8*>(W2t + u * 8);
    *reinterpret_cast<short8*>(&Wl2[n * 128 + ((k8 * 8) ^ ((n & 7) << 3))]) = v;
  }
  __syncthreads();
  int w = tid >> 6, l = tid & 63, g = l >> 4, c15 = l & 15;
  int swz = (c15 & 7) << 3;
  int abase = blockIdx.x * 64 + w * 16;
  bool active = abase < nAtoms;
  int ab = active ? abase : 0;
  int atom = ab + c15;
  int ar = (atom < nAtoms) ? atom : (nAtoms - 1);
  const float* hr = h + (size_t)ar * 64;
  short8 a[2];
#pragma unroll
  for (int ks = 0; ks < 2; ++ks) {
    float4 p0 = *(const float4*)(hr + ks * 32 + g * 8);
    float4 p1 = *(const float4*)(hr + ks * 32 + g * 8 + 4);
    union { unsigned u[4]; short8 s8; } pk;
    pk.u[0] = cvtpk(p0.x, p0.y); pk.u[1] = cvtpk(p0.z, p0.w);
    pk.u[2] = cvtpk(p1.x, p1.y); pk.u[3] = cvtpk(p1.z, p1.w);
    a[ks] = pk.s8;
  }
  ushort* R1w = R1[w];
#pragma unroll
  for (int nt = 0; nt < 8; ++nt) {
    float b = br1[nt * 16 + c15];
    f32x4 acc = {b, b, b, b};
    short8 B0 = *reinterpret_cast<const short8*>(&Wl1[(nt * 16 + c15) * 64 + ((g * 8) ^ swz)]);
    short8 B1 = *reinterpret_cast<const short8*>(&Wl1[(nt * 16 + c15) * 64 + ((32 + g * 8) ^ swz)]);
    acc = MFMA_BF16(a[0], B0, acc, 0, 0, 0);
    acc = MFMA_BF16(a[1], B1, acc, 0, 0, 0);
#pragma unroll
    for (int r = 0; r < 4; ++r) {
      int row = 4 * g + r;
      R1w[row * 136 + ((nt * 16 + c15) ^ ((row & 7) << 3))] = f2b(sftp(acc[r]));
    }
  }
  lds_fence();
  short8 a2[4];
#pragma unroll
  for (int ks = 0; ks < 4; ++ks)
    a2[ks] = *reinterpret_cast<const short8*>(&R1w[c15 * 136 + ((ks * 32 + g * 8) ^ swz)]);
  float lsum = 0.f;
#pragma unroll
  for (int nt = 0; nt < 4; ++nt) {
    float w3v = Wr3[nt * 16 + c15];
    float b = br2[nt * 16 + c15];
    f32x4 acc = {b, b, b, b};
#pragma unroll
    for (int ks = 0; ks < 4; ++ks) {
      short8 B = *reinterpret_cast<const short8*>(&Wl2[(nt * 16 + c15) * 128 + ((ks * 32 + g * 8) ^ swz)]);
      acc = MFMA_BF16(a2[ks], B, acc, 0, 0, 0);
    }
#pragma unroll
    for (int r = 0; r < 4; ++r) {
      int ao = ab + 4 * g + r;
      if (active && ao < nAtoms) lsum += sftp(acc[r]) * w3v;
    }
  }
  float tot = wsum64(lsum);
  if (l == 0) wsum[w] = tot;
  __syncthreads();
  if (tid == 0)
    partials[blockIdx.x] = wsum[0] + wsum[1] + wsum[2] + wsum[3];
}

// ---------------------------------------------------------------- readout (fp32 fallback)
__global__ __launch_bounds__(256) void k_readout(
    const float* __restrict__ h, const float* __restrict__ Wr1,
    const float* __restrict__ br1, const float* __restrict__ Wr2,
    const float* __restrict__ br2, const float* __restrict__ Wr3,
    float* __restrict__ partials, int nAtoms) {
  __shared__ float W1[64 * 128];
  __shared__ float W2[128 * 64];
  __shared__ float w3s[64];
  __shared__ float rowbuf[4][128];
  __shared__ float wsum[4];
  int tid = threadIdx.x;
  for (int t = tid; t < 2048; t += 256) {
    reinterpret_cast<float4*>(W1)[t] = reinterpret_cast<const float4*>(Wr1)[t];
    reinterpret_cast<float4*>(W2)[t] = reinterpret_cast<const float4*>(Wr2)[t];
  }
  if (tid < 64) w3s[tid] = Wr3[tid];
  __syncthreads();
  int w = tid >> 6, j = tid & 63;
  float b1a = br1[j], b1b = br1[64 + j], b2 = br2[j];
  float w3 = w3s[j];
  float lsum = 0.f;
  int wg = (blockIdx.x << 2) + w, nw = gridDim.x << 2;
  for (int n = wg; n < nAtoms; n += nw) {
    lds_fence();
    rowbuf[w][j] = h[(size_t)n * 64 + j];
    lds_fence();
    float a0 = b1a, a1 = b1b;
#pragma unroll
    for (int kk = 0; kk < 16; ++kk) {
      float4 q = *reinterpret_cast<const float4*>(&rowbuf[w][kk * 4]);
      const float* base = &W1[(kk * 4) * 128 + j];
      a0 += q.x * base[0] + q.y * base[128] + q.z * base[256] + q.w * base[384];
      a1 += q.x * base[64] + q.y * base[192] + q.z * base[320] + q.w * base[448];
    }
    a0 = sftp(a0);
    a1 = sftp(a1);
    lds_fence();
    rowbuf[w][j] = a0;
    rowbuf[w][64 + j] = a1;
    lds_fence();
    float a2 = b2;
#pragma unroll
    for (int kk = 0; kk < 32; ++kk) {
      float4 q = *reinterpret_cast<const float4*>(&rowbuf[w][kk * 4]);
      const float* base = &W2[(kk * 4) * 64 + j];
      a2 += q.x * base[0] + q.y * base[64] + q.z * base[128] + q.w * base[192];
    }
    lsum += sftp(a2) * w3;
  }
  float tot = wsum64(lsum);
  if (j == 0) wsum[w] = tot;
  __syncthreads();
  if (tid == 0)
    partials[blockIdx.x] = wsum[0] + wsum[1] + wsum[2] + wsum[3];
}

__global__ __launch_bounds__(256) void k_final(const float* __restrict__ partials,
                                               int nparts, float* __restrict__ out,
                                               const float* __restrict__ br3,
                                               float invN) {
  __shared__ float s[256];
  float v = 0.f;
  for (int t = threadIdx.x; t < nparts; t += 256) v += partials[t];
  s[threadIdx.x] = v;
  __syncthreads();
  for (int off = 128; off > 0; off >>= 1) {
    if (threadIdx.x < off) s[threadIdx.x] += s[threadIdx.x + off];
    __syncthreads();
  }
  if (threadIdx.x == 0) out[0] = s[0] * invN + br3[0];
}

// ---------------------------------------------------------------- launch
extern "C" void kernel_launch(void* const* d_in, const int* in_sizes, int n_in,
                              void* d_out, int out_size, void* d_ws, size_t ws_size,
                              hipStream_t stream) {
  const float* af   = (const float*)d_in[0];
  const float* nbrf = (const float*)d_in[1];
  const int*   idx  = (const int*)d_in[2];
  const float* Wemb = (const float*)d_in[3];
  const float* bemb = (const float*)d_in[4];
  const float* ln_s = (const float*)d_in[5];
  const float* ln_b = (const float*)d_in[6];
  const float* Wc   = (const float*)d_in[7];
  const float* bc   = (const float*)d_in[8];
  const float* Wn   = (const float*)d_in[9];
  const float* bn   = (const float*)d_in[10];
  const float* We   = (const float*)d_in[11];
  const float* be   = (const float*)d_in[12];
  const float* Wg   = (const float*)d_in[13];
  const float* bg   = (const float*)d_in[14];
  const float* Wm   = (const float*)d_in[15];
  const float* bm   = (const float*)d_in[16];
  const float* Wr1  = (const float*)d_in[17];
  const float* br1  = (const float*)d_in[18];
  const float* Wr2  = (const float*)d_in[19];
  const float* br2  = (const float*)d_in[20];
  const float* Wr3  = (const float*)d_in[21];
  const float* br3  = (const float*)d_in[22];

  int N = in_sizes[0] / RAWF;  // 50000
  size_t rows = (size_t)N * MN;
  float* ws = (float*)d_ws;
  size_t nc = (size_t)N * CF;
  float* h   = ws;
  float* pcb = ws + nc;
  float* partials = ws + 2 * nc;                 // 1024 floats
  ushort* Wt   = (ushort*)(partials + 1024);     // 12*4096 bf16
  ushort* Wtc  = Wt + 12 * 4096;                 // 3*4096
  ushort* Wet  = Wtc + 3 * 4096;                 // 64*96
  ushort* xbf  = Wet + 64 * 96;                  // nc
  ushort* afb  = xbf + nc;                       // N*96
  ushort* nbf  = afb + (size_t)N * 96;           // rows*48
  ushort* W1t  = nbf + rows * 48;                // 8192
  ushort* W2t  = W1t + 8192;                     // 8192
  size_t need = (size_t)((char*)(W2t + 8192) - (char*)d_ws);
  bool full = ws_size >= need;
  const int RO_GRID = 512;
  int gw = (N + 63) / 64;

  k_prep<<<12, 256, 0, stream>>>(Wn, We, Wg, Wm, be, Wt, full ? 1 : 0);
  if (full) {
    k_prep_c<<<3, 256, 0, stream>>>(Wc, Wtc);
    k_prep_emb<<<1, 256, 0, stream>>>(Wemb, Wet);
    k_prep_ro<<<32, 256, 0, stream>>>(Wr1, Wr2, W1t, W2t);
    k_prep_af<<<(N + 7) / 8, 256, 0, stream>>>(af, afb, N);
    k_prep_nbrf2<<<2048, 256, 0, stream>>>(nbrf, nbf, (unsigned)rows, 1);
    k_embed2<<<gw, 256, 0, stream>>>(afb, Wet, bemb, h, N);
    for (int i = 0; i < 3; ++i) {
      k_lnphic2<<<gw, 256, 0, stream>>>(h, ln_s + i * 64, ln_b + i * 64,
                                        Wtc + (size_t)i * 4096, bc + i * 64,
                                        xbf, pcb, N);
      k_conv_mfma12<<<N / 8, 256, 0, stream>>>(xbf, pcb, nbf, idx,
                                               Wt + (size_t)i * 4 * 4096,
                                               bn + i * 64,
                                               bg + i * 64, bm + i * 64, h);
    }
    k_readout2<<<gw, 256, 0, stream>>>(h, W1t, W2t, br1, br2, Wr3,
                                       partials, N);
    k_final<<<1, 256, 0, stream>>>(partials, gw, (float*)d_out, br3, 1.f / N);
  } else {
    k_prep_nbrf2<<<2048, 256, 0, stream>>>(nbrf, nbf, (unsigned)rows, 0);
    k_embed<<<1024, 256, 0, stream>>>(af, Wemb, bemb, h, N);
    for (int i = 0; i < 3; ++i) {
      k_ln_phic<<<1024, 256, 0, stream>>>(h, ln_s + i * 64, ln_b + i * 64,
                                          Wc + i * 4096, bc + i * 64,
                                          xbf, pcb, N);
      k_conv_mfma2<<<N / 8, 256, 0, stream>>>(xbf, pcb, nbf, idx,
                                              Wt + (size_t)i * 4 * 4096,
                                              bn + i * 64, be + i * 64,
                                              bg + i * 64, bm + i * 64, h);
    }
    k_readout<<<RO_GRID, 256, 0, stream>>>(h, Wr1, br1, Wr2, br2, Wr3,
                                           partials, N);
    k_final<<<1, 256, 0, stream>>>(partials, RO_GRID, (float*)d_out, br3, 1.f / N);
  }
}